// Round 8
// baseline (1119.244 us; speedup 1.0000x reference)
//
#include <hip/hip_runtime.h>
#include <hip/hip_fp16.h>
#include <math.h>

#define HID   64
#define HEADS 4
#define DH    16
#define NU    30000
#define NE_   60000
#define NV    1000
#define NTOT  91000
#define ETOT  870000
#define NSLOT 541000
#define LAYERS 2

// Edge-type tables
__device__ const int d_EOFF[14] = {0,150000,270000,330000,370000,400000,450000,
                                   570000,630000,670000,700000,750000,810000,870000};
__device__ const int d_ECNT[13] = {150000,120000,60000,40000,30000,50000,
                                   120000,60000,40000,30000,50000,60000,60000};
__device__ const int d_EST[13]  = {0,0,0,0,0,0,1,1,1,1,1,1,2};
__device__ const int d_EDT[13]  = {0,1,1,1,1,1,0,0,0,0,0,2,1};
__device__ const int d_NOFF[3]  = {0, NU, NU + NE_};
// slot base per edge type in the kvt mega-table (src-node indexed per e)
__device__ const int d_EBASE[13] = {0,30000,60000,90000,120000,150000,
                                    180000,240000,300000,360000,420000,480000,540000};

struct EdgePtrs { const int* p[13]; };

__device__ __forceinline__ int node_type(int n) {
    return (n >= NU) + (n >= NU + NE_);
}

// ---------------- input projection: h = x@W + b + emb[ids] ----------------
__global__ void k_init(const float* __restrict__ xu, const float* __restrict__ xe,
                       const float* __restrict__ xv,
                       const float* __restrict__ Wu, const float* __restrict__ bu,
                       const float* __restrict__ We, const float* __restrict__ be,
                       const float* __restrict__ Wv_, const float* __restrict__ bv,
                       const float* __restrict__ embu, const float* __restrict__ embe,
                       const float* __restrict__ embv,
                       const int* __restrict__ idu, const int* __restrict__ ide,
                       const int* __restrict__ idv,
                       float* __restrict__ h) {
    int gid = blockIdx.x * blockDim.x + threadIdx.x;
    if (gid >= NTOT * HID) return;
    int node = gid >> 6, j = gid & 63;
    const float *x, *W, *b, *emb; const int* ids; int in_dim, n;
    if (node < NU)            { n = node;           x = xu; W = Wu;  b = bu; emb = embu; ids = idu; in_dim = 32; }
    else if (node < NU + NE_) { n = node - NU;      x = xe; W = We;  b = be; emb = embe; ids = ide; in_dim = 32; }
    else                      { n = node - NU - NE_;x = xv; W = Wv_; b = bv; emb = embv; ids = idv; in_dim = 16; }
    float acc = b[j] + emb[(size_t)ids[n] * HID + j];
    for (int i = 0; i < in_dim; i++) acc += x[(size_t)n * in_dim + i] * W[i * HID + j];
    h[gid] = acc;
}

// ---------------- CSR build (exact rows, entry = slot index) ----------------
__global__ void k_cnt(EdgePtrs ep, int* __restrict__ cnt) {
    int eidx = blockIdx.x * blockDim.x + threadIdx.x;
    if (eidx >= ETOT) return;
    int e = 0;
    #pragma unroll
    for (int i = 1; i < 13; i++) e += (eidx >= d_EOFF[i]);
    int li = eidx - d_EOFF[e];
    int dst = ep.p[e][d_ECNT[e] + li];
    atomicAdd(&cnt[d_NOFF[d_EDT[e]] + dst], 1);
}

__global__ void k_scan_a(const int* __restrict__ cnt, int* __restrict__ partial) {
    __shared__ int s[256];
    int i = blockIdx.x * 256 + threadIdx.x;
    s[threadIdx.x] = (i < NTOT) ? cnt[i] : 0;
    __syncthreads();
    for (int off = 128; off > 0; off >>= 1) {
        if (threadIdx.x < off) s[threadIdx.x] += s[threadIdx.x + off];
        __syncthreads();
    }
    if (threadIdx.x == 0) partial[blockIdx.x] = s[0];
}

__global__ void k_scan_b(int* __restrict__ partial, int nblk) {
    __shared__ int s[512];
    int t = threadIdx.x;
    s[t] = (t < nblk) ? partial[t] : 0;
    __syncthreads();
    for (int off = 1; off < 512; off <<= 1) {
        int v = (t >= off) ? s[t - off] : 0;
        __syncthreads();
        s[t] += v;
        __syncthreads();
    }
    if (t < nblk) partial[t] = t ? s[t - 1] : 0;   // exclusive
}

__global__ void k_scan_c(const int* __restrict__ cnt, const int* __restrict__ partial,
                         int* __restrict__ row_ptr) {
    __shared__ int s[256];
    int i = blockIdx.x * 256 + threadIdx.x, t = threadIdx.x;
    int v = (i < NTOT) ? cnt[i] : 0;
    s[t] = v;
    __syncthreads();
    for (int off = 1; off < 256; off <<= 1) {
        int u = (t >= off) ? s[t - off] : 0;
        __syncthreads();
        s[t] += u;
        __syncthreads();
    }
    if (i < NTOT) row_ptr[i] = s[t] - v + partial[blockIdx.x];
    if (i == NTOT - 1) row_ptr[NTOT] = s[t] + partial[blockIdx.x];
}

__global__ void k_fill(EdgePtrs ep, const int* __restrict__ row_ptr,
                       int* __restrict__ cursor, int* __restrict__ csr) {
    int eidx = blockIdx.x * blockDim.x + threadIdx.x;
    if (eidx >= ETOT) return;
    int e = 0;
    #pragma unroll
    for (int i = 1; i < 13; i++) e += (eidx >= d_EOFF[i]);
    int li = eidx - d_EOFF[e];
    const int* base = ep.p[e];
    int src = base[li], dst = base[d_ECNT[e] + li];
    int dg = d_NOFF[d_EDT[e]] + dst;
    int pos = atomicAdd(&cursor[dg], 1);
    csr[row_ptr[dg] + pos] = d_EBASE[e] + src;
}

// ---------------- fused kqv projection + kvt slot table build ----------------
// stage 1: kqv[16 nodes][192] -> LDS (fp32)
// stage 2: for each e with EST[e]==t: kvt[slot][h*16+x] =
//          half2( prel*scale * sum_d k[h,d]Wk[e,h,d,x], sum_d v[h,d]Wv[e,h,d,x] )
__global__ __launch_bounds__(192)
void k_kqvt(const float* __restrict__ h, const float* __restrict__ Wkqv,
            const float* __restrict__ bkqv, const float* __restrict__ Wk,
            const float* __restrict__ Wv, const float* __restrict__ prel,
            float* __restrict__ qagg, __half2* __restrict__ kvt, int layer) {
    int n0 = blockIdx.x * 16;
    if (n0 >= NTOT) return;
    int t = node_type(n0);          // 16-node tiles never straddle type boundaries
    int nn = min(16, NTOT - n0);
    __shared__ float hs[16][64];
    __shared__ float kq[16][192];   // per node: k 0..63 | q 64..127 | v 128..191
    for (int i = threadIdx.x; i < nn * 64; i += 192)
        hs[i >> 6][i & 63] = h[(size_t)n0 * 64 + i];
    __syncthreads();
    const float* W = Wkqv + (size_t)(layer * 3 + t) * HID * 192;
    int j = threadIdx.x;
    float b = bkqv[(layer * 3 + t) * 192 + j];
    float acc[16];
    #pragma unroll
    for (int n = 0; n < 16; n++) acc[n] = b;
    for (int i = 0; i < 64; i++) {
        float w = W[i * 192 + j];
        #pragma unroll
        for (int n = 0; n < 16; n++) acc[n] += hs[n][i] * w;
    }
    #pragma unroll
    for (int n = 0; n < 16; n++) kq[n][j] = acc[n];
    if (j >= 64 && j < 128)
        for (int n = 0; n < nn; n++) qagg[(size_t)(n0 + n) * 64 + (j - 64)] = acc[n];
    __syncthreads();
    // ---- stage 2: emit kvt slots for all edge types sourced by this node type
    int wave = j >> 6, lane = j & 63;
    int hh = lane >> 4, xo = lane & 15;
    int ne = (t == 2) ? 1 : 6;
    int e0 = (t == 0) ? 0 : (t == 1) ? 6 : 12;
    for (int rep = wave; rep < ne; rep += 3) {
        int e = e0 + rep;
        const float* Wkp = Wk + (((size_t)layer * 13 + e) * 4 + hh) * 256 + xo;
        const float* Wvp = Wv + (((size_t)layer * 13 + e) * 4 + hh) * 256 + xo;
        float pr = prel[(layer * 13 + e) * 4 + hh] * 0.25f;
        float wk[16], wv[16];
        #pragma unroll
        for (int d = 0; d < 16; d++) { wk[d] = Wkp[d * 16] * pr; wv[d] = Wvp[d * 16]; }
        int sbase = d_EBASE[e] + (n0 - d_NOFF[t]);
        for (int n = 0; n < nn; n++) {
            const float* kr = &kq[n][hh * 16];
            const float* vr = &kq[n][128 + hh * 16];
            float kt = 0.f, vt = 0.f;
            #pragma unroll
            for (int d = 0; d < 16; d++) { kt += kr[d] * wk[d]; vt += vr[d] * wv[d]; }
            kvt[(size_t)(sbase + n) * 64 + lane] = __float22half2_rn(make_float2(kt, vt));
        }
    }
}

// ---------------- fused gather: 2 adjacent nodes per wave (contiguous csr span)
__global__ __launch_bounds__(512)
void k_gather(float* __restrict__ qagg, const __half2* __restrict__ kvt,
              const int* __restrict__ row_ptr, const int* __restrict__ csr) {
    int wave = threadIdx.x >> 6, lane = threadIdx.x & 63;
    int nA = blockIdx.x * 16 + wave * 2;
    if (nA >= NTOT) return;
    bool hasB = (nA + 1) < NTOT;
    float qA = qagg[(size_t)nA * 64 + lane];
    float qB = hasB ? qagg[(size_t)(nA + 1) * 64 + lane] : 0.f;
    int beg    = row_ptr[nA];
    int endA   = row_ptr[nA + 1];
    int endAll = hasB ? row_ptr[nA + 2] : endA;
    float mA = -1e30f, lA = 0.f, aA = 0.f;
    float mB = -1e30f, lB = 0.f, aB = 0.f;
    for (int base = beg; base < endAll; base += 64) {
        int n = endAll - base; if (n > 64) n = 64;
        int ent = csr[base + ((lane < n) ? lane : 0)];   // 64 entries, one load
        for (int c = 0; c < n; c += 16) {
            int cn = n - c; if (cn > 16) cn = 16;
            __half2 f[16];
            #pragma unroll
            for (int k = 0; k < 16; k++) {               // masked gather batch
                if (k < cn) {                            // wave-uniform
                    int sl = __shfl(ent, c + k, 64);
                    f[k] = kvt[(size_t)sl * 64 + lane];
                }
            }
            #pragma unroll
            for (int k = 0; k < 16; k++) {
                if (k >= cn) break;
                int idx = base + c + k;
                float2 kv2 = __half22float2(f[k]);
                bool isA = idx < endA;                   // wave-uniform stream split
                float s = (isA ? qA : qB) * kv2.x;
                s += __shfl_xor(s, 1, 64); s += __shfl_xor(s, 2, 64);
                s += __shfl_xor(s, 4, 64); s += __shfl_xor(s, 8, 64);
                if (isA) {
                    float d = s - mA;
                    float tt = __expf(-fabsf(d));
                    bool pos = d > 0.f;
                    mA = fmaxf(mA, s);
                    float sc = pos ? tt : 1.f, es = pos ? 1.f : tt;
                    lA = lA * sc + es;  aA = aA * sc + es * kv2.y;
                } else {
                    float d = s - mB;
                    float tt = __expf(-fabsf(d));
                    bool pos = d > 0.f;
                    mB = fmaxf(mB, s);
                    float sc = pos ? tt : 1.f, es = pos ? 1.f : tt;
                    lB = lB * sc + es;  aB = aB * sc + es * kv2.y;
                }
            }
        }
    }
    qagg[(size_t)nA * 64 + lane] = (lA > 0.f) ? aA / lA : 0.f;
    if (hasB) qagg[(size_t)(nA + 1) * 64 + lane] = (lB > 0.f) ? aB / lB : 0.f;
}

// ------- epilogue: gelu -> @Wout + bout -> skip-gate -> relu [-> l2norm on last]
__global__ __launch_bounds__(256)
void k_out(const float* __restrict__ agg, const float* __restrict__ Wout,
           const float* __restrict__ bout, const float* __restrict__ skip,
           float* __restrict__ h, float* __restrict__ out, int layer, int last) {
    int b = blockIdx.x; int t, n0, lim;
    if (b < 938)       { t = 0; n0 = b * 32;                 lim = NU; }
    else if (b < 2813) { t = 1; n0 = NU + (b - 938) * 32;    lim = NU + NE_; }
    else               { t = 2; n0 = NU + NE_ + (b - 2813) * 32; lim = NTOT; }
    int nn = min(32, lim - n0);
    __shared__ float gs[32][64];
    for (int i = threadIdx.x; i < nn * 64; i += 256) {
        float o = agg[(size_t)n0 * 64 + i];
        gs[i >> 6][i & 63] = 0.5f * o * (1.f + erff(o * 0.70710678118654752f));
    }
    __syncthreads();
    int j = threadIdx.x & 63, g = threadIdx.x >> 6;   // 4 waves x 8 nodes
    const float* W = Wout + (size_t)(layer * 3 + t) * HID * HID;
    float bb = bout[(layer * 3 + t) * HID + j];
    float acc[8];
    #pragma unroll
    for (int n = 0; n < 8; n++) acc[n] = bb;
    for (int i = 0; i < 64; i++) {
        float w = W[i * 64 + j];
        #pragma unroll
        for (int n = 0; n < 8; n++) acc[n] += gs[g * 8 + n][i] * w;
    }
    float gk = 1.f / (1.f + __expf(-skip[layer * 3 + t]));
    #pragma unroll
    for (int n = 0; n < 8; n++) {
        int node = n0 + g * 8 + n;
        if (node >= lim) continue;
        float r = gk * acc[n] + (1.f - gk) * h[(size_t)node * 64 + j];
        r = fmaxf(r, 0.f);                              // relu
        if (!last) {
            h[(size_t)node * 64 + j] = r;
        } else {                                        // fused l2 normalize
            float ss = r * r;
            ss += __shfl_xor(ss, 1, 64);  ss += __shfl_xor(ss, 2, 64);
            ss += __shfl_xor(ss, 4, 64);  ss += __shfl_xor(ss, 8, 64);
            ss += __shfl_xor(ss, 16, 64); ss += __shfl_xor(ss, 32, 64);
            float nrm = fmaxf(sqrtf(ss), 1e-12f);
            out[(size_t)node * 64 + j] = r / nrm;
        }
    }
}

extern "C" void kernel_launch(void* const* d_in, const int* in_sizes, int n_in,
                              void* d_out, int out_size, void* d_ws, size_t ws_size,
                              hipStream_t stream) {
    const float* xu   = (const float*)d_in[0];
    const float* xe   = (const float*)d_in[1];
    const float* xv   = (const float*)d_in[2];
    const float* Wu   = (const float*)d_in[3];
    const float* bu   = (const float*)d_in[4];
    const float* We   = (const float*)d_in[5];
    const float* be   = (const float*)d_in[6];
    const float* Wv_  = (const float*)d_in[7];
    const float* bv   = (const float*)d_in[8];
    const float* embu = (const float*)d_in[9];
    const float* embe = (const float*)d_in[10];
    const float* embv = (const float*)d_in[11];
    const float* Wkqv = (const float*)d_in[12];
    const float* bkqv = (const float*)d_in[13];
    const float* Wk   = (const float*)d_in[14];
    const float* Wv   = (const float*)d_in[15];
    const float* prel = (const float*)d_in[16];
    const float* Wout = (const float*)d_in[17];
    const float* bout = (const float*)d_in[18];
    const float* skip = (const float*)d_in[19];
    const int*   idu  = (const int*)d_in[20];
    const int*   ide  = (const int*)d_in[21];
    const int*   idv  = (const int*)d_in[22];
    EdgePtrs ep;
    for (int e = 0; e < 13; e++) ep.p[e] = (const int*)d_in[23 + e];

    float* ws  = (float*)d_ws;
    float* h      = ws;                                    // NTOT*64 f32
    float* qagg   = h    + (size_t)NTOT * HID;             // NTOT*64 f32 (q, then agg)
    __half2* kvt  = (__half2*)(qagg + (size_t)NTOT * HID); // NSLOT*64 half2
    int* cnt     = (int*)(kvt + (size_t)NSLOT * HID);      // NTOT
    int* cursor  = cnt + NTOT;                             // NTOT
    int* row_ptr = cursor + NTOT;                          // NTOT+1
    int* partial = row_ptr + NTOT + 1;                     // 512
    int* csr     = partial + 512;                          // ETOT int

    k_init<<<(NTOT * HID + 255) / 256, 256, 0, stream>>>(
        xu, xe, xv, Wu, bu, We, be, Wv_, bv, embu, embe, embv, idu, ide, idv, h);

    // CSR build (edges are layer-invariant); exact rows, entry = slot id
    hipMemsetAsync(cnt, 0, (size_t)2 * NTOT * 4, stream);   // cnt + cursor
    int nblk = (NTOT + 255) / 256;   // 356
    k_cnt<<<(ETOT + 255) / 256, 256, 0, stream>>>(ep, cnt);
    k_scan_a<<<nblk, 256, 0, stream>>>(cnt, partial);
    k_scan_b<<<1, 512, 0, stream>>>(partial, nblk);
    k_scan_c<<<nblk, 256, 0, stream>>>(cnt, partial, row_ptr);
    k_fill<<<(ETOT + 255) / 256, 256, 0, stream>>>(ep, row_ptr, cursor, csr);

    for (int l = 0; l < LAYERS; l++) {
        k_kqvt<<<(NTOT + 15) / 16, 192, 0, stream>>>(h, Wkqv, bkqv, Wk, Wv, prel,
                                                     qagg, kvt, l);
        k_gather<<<(NTOT + 15) / 16, 512, 0, stream>>>(qagg, kvt, row_ptr, csr);
        k_out<<<2845, 256, 0, stream>>>(qagg, Wout, bout, skip, h,
                                        (float*)d_out, l, l == LAYERS - 1);
    }
}

// Round 9
// 862.767 us; speedup vs baseline: 1.2973x; 1.2973x over previous
//
#include <hip/hip_runtime.h>
#include <hip/hip_fp16.h>
#include <math.h>

#define HID   64
#define HEADS 4
#define DH    16
#define NU    30000
#define NE_   60000
#define NV    1000
#define NTOT  91000
#define ETOT  870000
#define NSLOT 541000
#define LAYERS 2

// Edge-type tables
__device__ const int d_EOFF[14] = {0,150000,270000,330000,370000,400000,450000,
                                   570000,630000,670000,700000,750000,810000,870000};
__device__ const int d_ECNT[13] = {150000,120000,60000,40000,30000,50000,
                                   120000,60000,40000,30000,50000,60000,60000};
__device__ const int d_EST[13]  = {0,0,0,0,0,0,1,1,1,1,1,1,2};
__device__ const int d_EDT[13]  = {0,1,1,1,1,1,0,0,0,0,0,2,1};
__device__ const int d_NOFF[3]  = {0, NU, NU + NE_};
// slot base per edge type in the kvt mega-table (src-node indexed per e)
__device__ const int d_EBASE[13] = {0,30000,60000,90000,120000,150000,
                                    180000,240000,300000,360000,420000,480000,540000};

struct EdgePtrs { const int* p[13]; };

__device__ __forceinline__ int node_type(int n) {
    return (n >= NU) + (n >= NU + NE_);
}

// ---------------- input projection: h = x@W + b + emb[ids] ----------------
__global__ void k_init(const float* __restrict__ xu, const float* __restrict__ xe,
                       const float* __restrict__ xv,
                       const float* __restrict__ Wu, const float* __restrict__ bu,
                       const float* __restrict__ We, const float* __restrict__ be,
                       const float* __restrict__ Wv_, const float* __restrict__ bv,
                       const float* __restrict__ embu, const float* __restrict__ embe,
                       const float* __restrict__ embv,
                       const int* __restrict__ idu, const int* __restrict__ ide,
                       const int* __restrict__ idv,
                       float* __restrict__ h) {
    int gid = blockIdx.x * blockDim.x + threadIdx.x;
    if (gid >= NTOT * HID) return;
    int node = gid >> 6, j = gid & 63;
    const float *x, *W, *b, *emb; const int* ids; int in_dim, n;
    if (node < NU)            { n = node;           x = xu; W = Wu;  b = bu; emb = embu; ids = idu; in_dim = 32; }
    else if (node < NU + NE_) { n = node - NU;      x = xe; W = We;  b = be; emb = embe; ids = ide; in_dim = 32; }
    else                      { n = node - NU - NE_;x = xv; W = Wv_; b = bv; emb = embv; ids = idv; in_dim = 16; }
    float acc = b[j] + emb[(size_t)ids[n] * HID + j];
    for (int i = 0; i < in_dim; i++) acc += x[(size_t)n * in_dim + i] * W[i * HID + j];
    h[gid] = acc;
}

// ---------------- CSR build (exact rows, entry = slot index) ----------------
__global__ void k_cnt(EdgePtrs ep, int* __restrict__ cnt) {
    int eidx = blockIdx.x * blockDim.x + threadIdx.x;
    if (eidx >= ETOT) return;
    int e = 0;
    #pragma unroll
    for (int i = 1; i < 13; i++) e += (eidx >= d_EOFF[i]);
    int li = eidx - d_EOFF[e];
    int dst = ep.p[e][d_ECNT[e] + li];
    atomicAdd(&cnt[d_NOFF[d_EDT[e]] + dst], 1);
}

__global__ void k_scan_a(const int* __restrict__ cnt, int* __restrict__ partial) {
    __shared__ int s[256];
    int i = blockIdx.x * 256 + threadIdx.x;
    s[threadIdx.x] = (i < NTOT) ? cnt[i] : 0;
    __syncthreads();
    for (int off = 128; off > 0; off >>= 1) {
        if (threadIdx.x < off) s[threadIdx.x] += s[threadIdx.x + off];
        __syncthreads();
    }
    if (threadIdx.x == 0) partial[blockIdx.x] = s[0];
}

__global__ void k_scan_b(int* __restrict__ partial, int nblk) {
    __shared__ int s[512];
    int t = threadIdx.x;
    s[t] = (t < nblk) ? partial[t] : 0;
    __syncthreads();
    for (int off = 1; off < 512; off <<= 1) {
        int v = (t >= off) ? s[t - off] : 0;
        __syncthreads();
        s[t] += v;
        __syncthreads();
    }
    if (t < nblk) partial[t] = t ? s[t - 1] : 0;   // exclusive
}

__global__ void k_scan_c(const int* __restrict__ cnt, const int* __restrict__ partial,
                         int* __restrict__ row_ptr) {
    __shared__ int s[256];
    int i = blockIdx.x * 256 + threadIdx.x, t = threadIdx.x;
    int v = (i < NTOT) ? cnt[i] : 0;
    s[t] = v;
    __syncthreads();
    for (int off = 1; off < 256; off <<= 1) {
        int u = (t >= off) ? s[t - off] : 0;
        __syncthreads();
        s[t] += u;
        __syncthreads();
    }
    if (i < NTOT) row_ptr[i] = s[t] - v + partial[blockIdx.x];
    if (i == NTOT - 1) row_ptr[NTOT] = s[t] + partial[blockIdx.x];
}

__global__ void k_fill(EdgePtrs ep, const int* __restrict__ row_ptr,
                       int* __restrict__ cursor, int* __restrict__ csr) {
    int eidx = blockIdx.x * blockDim.x + threadIdx.x;
    if (eidx >= ETOT) return;
    int e = 0;
    #pragma unroll
    for (int i = 1; i < 13; i++) e += (eidx >= d_EOFF[i]);
    int li = eidx - d_EOFF[e];
    const int* base = ep.p[e];
    int src = base[li], dst = base[d_ECNT[e] + li];
    int dg = d_NOFF[d_EDT[e]] + dst;
    int pos = atomicAdd(&cursor[dg], 1);
    csr[row_ptr[dg] + pos] = d_EBASE[e] + src;
}

// ---------------- fused kqv projection + kvt slot table build ----------------
// stage 1: kqv[16 nodes][192] -> LDS (fp32)
// stage 2: for each e with EST[e]==t: kvt[slot][h*16+x] =
//          half2( prel*scale * sum_d k[h,d]Wk[e,h,d,x], sum_d v[h,d]Wv[e,h,d,x] )
__global__ __launch_bounds__(192)
void k_kqvt(const float* __restrict__ h, const float* __restrict__ Wkqv,
            const float* __restrict__ bkqv, const float* __restrict__ Wk,
            const float* __restrict__ Wv, const float* __restrict__ prel,
            float* __restrict__ qagg, __half2* __restrict__ kvt, int layer) {
    int n0 = blockIdx.x * 16;
    if (n0 >= NTOT) return;
    int t = node_type(n0);          // 16-node tiles never straddle type boundaries
    int nn = min(16, NTOT - n0);
    __shared__ float hs[16][64];
    __shared__ float kq[16][192];   // per node: k 0..63 | q 64..127 | v 128..191
    for (int i = threadIdx.x; i < nn * 64; i += 192)
        hs[i >> 6][i & 63] = h[(size_t)n0 * 64 + i];
    __syncthreads();
    const float* W = Wkqv + (size_t)(layer * 3 + t) * HID * 192;
    int j = threadIdx.x;
    float b = bkqv[(layer * 3 + t) * 192 + j];
    float acc[16];
    #pragma unroll
    for (int n = 0; n < 16; n++) acc[n] = b;
    for (int i = 0; i < 64; i++) {
        float w = W[i * 192 + j];
        #pragma unroll
        for (int n = 0; n < 16; n++) acc[n] += hs[n][i] * w;
    }
    #pragma unroll
    for (int n = 0; n < 16; n++) kq[n][j] = acc[n];
    if (j >= 64 && j < 128)
        for (int n = 0; n < nn; n++) qagg[(size_t)(n0 + n) * 64 + (j - 64)] = acc[n];
    __syncthreads();
    // ---- stage 2: emit kvt slots for all edge types sourced by this node type
    int wave = j >> 6, lane = j & 63;
    int hh = lane >> 4, xo = lane & 15;
    int ne = (t == 2) ? 1 : 6;
    int e0 = (t == 0) ? 0 : (t == 1) ? 6 : 12;
    for (int rep = wave; rep < ne; rep += 3) {
        int e = e0 + rep;
        const float* Wkp = Wk + (((size_t)layer * 13 + e) * 4 + hh) * 256 + xo;
        const float* Wvp = Wv + (((size_t)layer * 13 + e) * 4 + hh) * 256 + xo;
        float pr = prel[(layer * 13 + e) * 4 + hh] * 0.25f;
        float wk[16], wv[16];
        #pragma unroll
        for (int d = 0; d < 16; d++) { wk[d] = Wkp[d * 16] * pr; wv[d] = Wvp[d * 16]; }
        int sbase = d_EBASE[e] + (n0 - d_NOFF[t]);
        for (int n = 0; n < nn; n++) {
            const float* kr = &kq[n][hh * 16];
            const float* vr = &kq[n][128 + hh * 16];
            float kt = 0.f, vt = 0.f;
            #pragma unroll
            for (int d = 0; d < 16; d++) { kt += kr[d] * wk[d]; vt += vr[d] * wv[d]; }
            kvt[(size_t)(sbase + n) * 64 + lane] = __float22half2_rn(make_float2(kt, vt));
        }
    }
}

// -------- fused gather: score + online softmax + message agg (R6 codegen) --------
__global__ __launch_bounds__(512)
void k_gather(float* __restrict__ qagg, const __half2* __restrict__ kvt,
              const int* __restrict__ row_ptr, const int* __restrict__ csr) {
    int wave = threadIdx.x >> 6, lane = threadIdx.x & 63;
    int node = blockIdx.x * 8 + wave;
    if (node >= NTOT) return;
    float q = qagg[(size_t)node * 64 + lane];   // q[h][x]
    int beg = row_ptr[node], end = row_ptr[node + 1];
    float m = -1e30f, l = 0.f, acc = 0.f;
    for (int base = beg; base < end; base += 64) {
        int n = end - base; if (n > 64) n = 64;
        int ent = csr[base + ((lane < n) ? lane : 0)];   // 64 entries in one load
        for (int c = 0; c < n; c += 8) {
            int cn = n - c; if (cn > 8) cn = 8;
            __half2 f[8];
            #pragma unroll
            for (int k = 0; k < 8; k++) {               // batch 8 gathers (MLP)
                int idx = c + ((k < cn) ? k : 0);
                int sl = __shfl(ent, idx, 64);
                f[k] = kvt[(size_t)sl * 64 + lane];
            }
            #pragma unroll
            for (int k = 0; k < 8; k++) {
                if (k >= cn) break;
                float2 kv2 = __half22float2(f[k]);
                float s = q * kv2.x;
                s += __shfl_xor(s, 1, 64); s += __shfl_xor(s, 2, 64);
                s += __shfl_xor(s, 4, 64); s += __shfl_xor(s, 8, 64);
                float d2 = s - m;
                float t = __expf(-fabsf(d2));   // one exp per edge
                bool pos = d2 > 0.f;
                m = fmaxf(m, s);
                float sc1 = pos ? t : 1.f;
                float es  = pos ? 1.f : t;
                l   = l * sc1 + es;
                acc = acc * sc1 + es * kv2.y;
            }
        }
    }
    qagg[(size_t)node * 64 + lane] = (l > 0.f) ? acc / l : 0.f;
}

// ------- epilogue: gelu -> @Wout + bout -> skip-gate -> relu [-> l2norm on last]
__global__ __launch_bounds__(256)
void k_out(const float* __restrict__ agg, const float* __restrict__ Wout,
           const float* __restrict__ bout, const float* __restrict__ skip,
           float* __restrict__ h, float* __restrict__ out, int layer, int last) {
    int b = blockIdx.x; int t, n0, lim;
    if (b < 938)       { t = 0; n0 = b * 32;                 lim = NU; }
    else if (b < 2813) { t = 1; n0 = NU + (b - 938) * 32;    lim = NU + NE_; }
    else               { t = 2; n0 = NU + NE_ + (b - 2813) * 32; lim = NTOT; }
    int nn = min(32, lim - n0);
    __shared__ float gs[32][64];
    for (int i = threadIdx.x; i < nn * 64; i += 256) {
        float o = agg[(size_t)n0 * 64 + i];
        gs[i >> 6][i & 63] = 0.5f * o * (1.f + erff(o * 0.70710678118654752f));
    }
    __syncthreads();
    int j = threadIdx.x & 63, g = threadIdx.x >> 6;   // 4 waves x 8 nodes
    const float* W = Wout + (size_t)(layer * 3 + t) * HID * HID;
    float bb = bout[(layer * 3 + t) * HID + j];
    float acc[8];
    #pragma unroll
    for (int n = 0; n < 8; n++) acc[n] = bb;
    for (int i = 0; i < 64; i++) {
        float w = W[i * 64 + j];
        #pragma unroll
        for (int n = 0; n < 8; n++) acc[n] += gs[g * 8 + n][i] * w;
    }
    float gk = 1.f / (1.f + __expf(-skip[layer * 3 + t]));
    #pragma unroll
    for (int n = 0; n < 8; n++) {
        int node = n0 + g * 8 + n;
        if (node >= lim) continue;
        float r = gk * acc[n] + (1.f - gk) * h[(size_t)node * 64 + j];
        r = fmaxf(r, 0.f);                              // relu
        if (!last) {
            h[(size_t)node * 64 + j] = r;
        } else {                                        // fused l2 normalize
            float ss = r * r;
            ss += __shfl_xor(ss, 1, 64);  ss += __shfl_xor(ss, 2, 64);
            ss += __shfl_xor(ss, 4, 64);  ss += __shfl_xor(ss, 8, 64);
            ss += __shfl_xor(ss, 16, 64); ss += __shfl_xor(ss, 32, 64);
            float nrm = fmaxf(sqrtf(ss), 1e-12f);
            out[(size_t)node * 64 + j] = r / nrm;
        }
    }
}

extern "C" void kernel_launch(void* const* d_in, const int* in_sizes, int n_in,
                              void* d_out, int out_size, void* d_ws, size_t ws_size,
                              hipStream_t stream) {
    const float* xu   = (const float*)d_in[0];
    const float* xe   = (const float*)d_in[1];
    const float* xv   = (const float*)d_in[2];
    const float* Wu   = (const float*)d_in[3];
    const float* bu   = (const float*)d_in[4];
    const float* We   = (const float*)d_in[5];
    const float* be   = (const float*)d_in[6];
    const float* Wv_  = (const float*)d_in[7];
    const float* bv   = (const float*)d_in[8];
    const float* embu = (const float*)d_in[9];
    const float* embe = (const float*)d_in[10];
    const float* embv = (const float*)d_in[11];
    const float* Wkqv = (const float*)d_in[12];
    const float* bkqv = (const float*)d_in[13];
    const float* Wk   = (const float*)d_in[14];
    const float* Wv   = (const float*)d_in[15];
    const float* prel = (const float*)d_in[16];
    const float* Wout = (const float*)d_in[17];
    const float* bout = (const float*)d_in[18];
    const float* skip = (const float*)d_in[19];
    const int*   idu  = (const int*)d_in[20];
    const int*   ide  = (const int*)d_in[21];
    const int*   idv  = (const int*)d_in[22];
    EdgePtrs ep;
    for (int e = 0; e < 13; e++) ep.p[e] = (const int*)d_in[23 + e];

    float* ws  = (float*)d_ws;
    float* h      = ws;                                    // NTOT*64 f32
    float* qagg   = h    + (size_t)NTOT * HID;             // NTOT*64 f32 (q, then agg)
    __half2* kvt  = (__half2*)(qagg + (size_t)NTOT * HID); // NSLOT*64 half2
    int* cnt     = (int*)(kvt + (size_t)NSLOT * HID);      // NTOT
    int* cursor  = cnt + NTOT;                             // NTOT
    int* row_ptr = cursor + NTOT;                          // NTOT+1
    int* partial = row_ptr + NTOT + 1;                     // 512
    int* csr     = partial + 512;                          // ETOT int

    k_init<<<(NTOT * HID + 255) / 256, 256, 0, stream>>>(
        xu, xe, xv, Wu, bu, We, be, Wv_, bv, embu, embe, embv, idu, ide, idv, h);

    // CSR build (edges are layer-invariant); exact rows, entry = slot id
    hipMemsetAsync(cnt, 0, (size_t)2 * NTOT * 4, stream);   // cnt + cursor
    int nblk = (NTOT + 255) / 256;   // 356
    k_cnt<<<(ETOT + 255) / 256, 256, 0, stream>>>(ep, cnt);
    k_scan_a<<<nblk, 256, 0, stream>>>(cnt, partial);
    k_scan_b<<<1, 512, 0, stream>>>(partial, nblk);
    k_scan_c<<<nblk, 256, 0, stream>>>(cnt, partial, row_ptr);
    k_fill<<<(ETOT + 255) / 256, 256, 0, stream>>>(ep, row_ptr, cursor, csr);

    for (int l = 0; l < LAYERS; l++) {
        k_kqvt<<<(NTOT + 15) / 16, 192, 0, stream>>>(h, Wkqv, bkqv, Wk, Wv, prel,
                                                     qagg, kvt, l);
        k_gather<<<(NTOT + 7) / 8, 512, 0, stream>>>(qagg, kvt, row_ptr, csr);
        k_out<<<2845, 256, 0, stream>>>(qagg, Wout, bout, skip, h,
                                        (float*)d_out, l, l == LAYERS - 1);
    }
}

// Round 10
// 824.466 us; speedup vs baseline: 1.3575x; 1.0465x over previous
//
#include <hip/hip_runtime.h>
#include <hip/hip_fp16.h>
#include <math.h>

#define HID   64
#define HEADS 4
#define DH    16
#define NU    30000
#define NE_   60000
#define NV    1000
#define NTOT  91000
#define ETOT  870000
#define NSLOT 541000
#define LAYERS 2

// Edge-type tables
__device__ const int d_EOFF[14] = {0,150000,270000,330000,370000,400000,450000,
                                   570000,630000,670000,700000,750000,810000,870000};
__device__ const int d_ECNT[13] = {150000,120000,60000,40000,30000,50000,
                                   120000,60000,40000,30000,50000,60000,60000};
__device__ const int d_EST[13]  = {0,0,0,0,0,0,1,1,1,1,1,1,2};
__device__ const int d_EDT[13]  = {0,1,1,1,1,1,0,0,0,0,0,2,1};
__device__ const int d_NOFF[3]  = {0, NU, NU + NE_};
// slot base per edge type in the kvt mega-table (src-node indexed per e)
__device__ const int d_EBASE[13] = {0,30000,60000,90000,120000,150000,
                                    180000,240000,300000,360000,420000,480000,540000};

struct EdgePtrs { const int* p[13]; };

__device__ __forceinline__ int node_type(int n) {
    return (n >= NU) + (n >= NU + NE_);
}

__device__ __forceinline__ float dot16(const float4 a0, const float4 a1,
                                       const float4 a2, const float4 a3,
                                       const float* w) {
    return a0.x*w[0] + a0.y*w[1] + a0.z*w[2] + a0.w*w[3]
         + a1.x*w[4] + a1.y*w[5] + a1.z*w[6] + a1.w*w[7]
         + a2.x*w[8] + a2.y*w[9] + a2.z*w[10]+ a2.w*w[11]
         + a3.x*w[12]+ a3.y*w[13]+ a3.z*w[14]+ a3.w*w[15];
}

// ---------------- input projection: h = x@W + b + emb[ids] ----------------
__global__ void k_init(const float* __restrict__ xu, const float* __restrict__ xe,
                       const float* __restrict__ xv,
                       const float* __restrict__ Wu, const float* __restrict__ bu,
                       const float* __restrict__ We, const float* __restrict__ be,
                       const float* __restrict__ Wv_, const float* __restrict__ bv,
                       const float* __restrict__ embu, const float* __restrict__ embe,
                       const float* __restrict__ embv,
                       const int* __restrict__ idu, const int* __restrict__ ide,
                       const int* __restrict__ idv,
                       float* __restrict__ h) {
    int gid = blockIdx.x * blockDim.x + threadIdx.x;
    if (gid >= NTOT * HID) return;
    int node = gid >> 6, j = gid & 63;
    const float *x, *W, *b, *emb; const int* ids; int in_dim, n;
    if (node < NU)            { n = node;           x = xu; W = Wu;  b = bu; emb = embu; ids = idu; in_dim = 32; }
    else if (node < NU + NE_) { n = node - NU;      x = xe; W = We;  b = be; emb = embe; ids = ide; in_dim = 32; }
    else                      { n = node - NU - NE_;x = xv; W = Wv_; b = bv; emb = embv; ids = idv; in_dim = 16; }
    float acc = b[j] + emb[(size_t)ids[n] * HID + j];
    for (int i = 0; i < in_dim; i++) acc += x[(size_t)n * in_dim + i] * W[i * HID + j];
    h[gid] = acc;
}

// ---------------- CSR build (exact rows, entry = slot index) ----------------
__global__ void k_cnt(EdgePtrs ep, int* __restrict__ cnt) {
    int eidx = blockIdx.x * blockDim.x + threadIdx.x;
    if (eidx >= ETOT) return;
    int e = 0;
    #pragma unroll
    for (int i = 1; i < 13; i++) e += (eidx >= d_EOFF[i]);
    int li = eidx - d_EOFF[e];
    int dst = ep.p[e][d_ECNT[e] + li];
    atomicAdd(&cnt[d_NOFF[d_EDT[e]] + dst], 1);
}

__global__ void k_scan_a(const int* __restrict__ cnt, int* __restrict__ partial) {
    __shared__ int s[256];
    int i = blockIdx.x * 256 + threadIdx.x;
    s[threadIdx.x] = (i < NTOT) ? cnt[i] : 0;
    __syncthreads();
    for (int off = 128; off > 0; off >>= 1) {
        if (threadIdx.x < off) s[threadIdx.x] += s[threadIdx.x + off];
        __syncthreads();
    }
    if (threadIdx.x == 0) partial[blockIdx.x] = s[0];
}

__global__ void k_scan_b(int* __restrict__ partial, int nblk) {
    __shared__ int s[512];
    int t = threadIdx.x;
    s[t] = (t < nblk) ? partial[t] : 0;
    __syncthreads();
    for (int off = 1; off < 512; off <<= 1) {
        int v = (t >= off) ? s[t - off] : 0;
        __syncthreads();
        s[t] += v;
        __syncthreads();
    }
    if (t < nblk) partial[t] = t ? s[t - 1] : 0;   // exclusive
}

__global__ void k_scan_c(const int* __restrict__ cnt, const int* __restrict__ partial,
                         int* __restrict__ row_ptr) {
    __shared__ int s[256];
    int i = blockIdx.x * 256 + threadIdx.x, t = threadIdx.x;
    int v = (i < NTOT) ? cnt[i] : 0;
    s[t] = v;
    __syncthreads();
    for (int off = 1; off < 256; off <<= 1) {
        int u = (t >= off) ? s[t - off] : 0;
        __syncthreads();
        s[t] += u;
        __syncthreads();
    }
    if (i < NTOT) row_ptr[i] = s[t] - v + partial[blockIdx.x];
    if (i == NTOT - 1) row_ptr[NTOT] = s[t] + partial[blockIdx.x];
}

__global__ void k_fill(EdgePtrs ep, const int* __restrict__ row_ptr,
                       int* __restrict__ cursor, int* __restrict__ csr) {
    int eidx = blockIdx.x * blockDim.x + threadIdx.x;
    if (eidx >= ETOT) return;
    int e = 0;
    #pragma unroll
    for (int i = 1; i < 13; i++) e += (eidx >= d_EOFF[i]);
    int li = eidx - d_EOFF[e];
    const int* base = ep.p[e];
    int src = base[li], dst = base[d_ECNT[e] + li];
    int dg = d_NOFF[d_EDT[e]] + dst;
    int pos = atomicAdd(&cursor[dg], 1);
    csr[row_ptr[dg] + pos] = d_EBASE[e] + src;
}

// ---------------- fused kqv projection + kvt slot table build ----------------
// stage 1: kqv for 16 nodes; W row cached in 64 VGPRs, h read as block-uniform
//          float4 (scalarizable) -- no LDS staging, no ds_read storm.
// stage 2: k/v rows read from LDS once per node (8 x b128), shared across the
//          wave's two edge types; full 16-unroll, uniform store guard.
__global__ __launch_bounds__(192, 4)
void k_kqvt(const float* __restrict__ h, const float* __restrict__ Wkqv,
            const float* __restrict__ bkqv, const float* __restrict__ Wk,
            const float* __restrict__ Wv, const float* __restrict__ prel,
            float* __restrict__ qagg, __half2* __restrict__ kvt, int layer) {
    int n0 = blockIdx.x * 16;
    int t = node_type(n0);          // 16-node tiles never straddle type boundaries
    __shared__ float kq[16][192];   // per node: k 0..63 | q 64..127 | v 128..191
    int j = threadIdx.x;
    const float* W = Wkqv + (size_t)(layer * 3 + t) * HID * 192;
    float wreg[64];
    #pragma unroll
    for (int i = 0; i < 64; i++) wreg[i] = W[i * 192 + j];
    float b = bkqv[(layer * 3 + t) * 192 + j];
    float acc[16];
    #pragma unroll
    for (int n = 0; n < 16; n++) acc[n] = b;
    const float* hb = h + (size_t)n0 * 64;
    #pragma unroll
    for (int ic = 0; ic < 16; ic++) {
        #pragma unroll
        for (int n = 0; n < 16; n++) {
            float4 hv = *(const float4*)(hb + n * 64 + ic * 4);  // block-uniform
            acc[n] += hv.x * wreg[4*ic]   + hv.y * wreg[4*ic+1]
                    + hv.z * wreg[4*ic+2] + hv.w * wreg[4*ic+3];
        }
    }
    #pragma unroll
    for (int n = 0; n < 16; n++) kq[n][j] = acc[n];
    if (j >= 64 && j < 128) {
        #pragma unroll
        for (int n = 0; n < 16; n++)
            if (n0 + n < NTOT) qagg[(size_t)(n0 + n) * 64 + (j - 64)] = acc[n];
    }
    __syncthreads();
    // ---- stage 2: emit kvt slots for the edge types sourced by this node type
    int wave = j >> 6, lane = j & 63;
    int hh = lane >> 4, xo = lane & 15;
    int ne = (t == 2) ? 1 : 6;
    int e0 = (t == 0) ? 0 : (t == 1) ? 6 : 12;
    int eA = e0 + wave, eB = e0 + wave + 3;
    bool vA = wave < ne, vB = wave + 3 < ne;
    int nt = n0 - d_NOFF[t];
    float wkA[16], wvA[16], wkB[16], wvB[16];
    int sbA = 0, sbB = 0;
    if (vA) {
        const float* Wkp = Wk + (((size_t)layer * 13 + eA) * 4 + hh) * 256 + xo;
        const float* Wvp = Wv + (((size_t)layer * 13 + eA) * 4 + hh) * 256 + xo;
        float pr = prel[(layer * 13 + eA) * 4 + hh] * 0.25f;
        #pragma unroll
        for (int d = 0; d < 16; d++) { wkA[d] = Wkp[d * 16] * pr; wvA[d] = Wvp[d * 16]; }
        sbA = d_EBASE[eA] + nt;
    }
    if (vB) {
        const float* Wkp = Wk + (((size_t)layer * 13 + eB) * 4 + hh) * 256 + xo;
        const float* Wvp = Wv + (((size_t)layer * 13 + eB) * 4 + hh) * 256 + xo;
        float pr = prel[(layer * 13 + eB) * 4 + hh] * 0.25f;
        #pragma unroll
        for (int d = 0; d < 16; d++) { wkB[d] = Wkp[d * 16] * pr; wvB[d] = Wvp[d * 16]; }
        sbB = d_EBASE[eB] + nt;
    }
    #pragma unroll
    for (int n = 0; n < 16; n++) {
        bool ok = (n0 + n) < NTOT;                 // uniform; false only in tail tile
        const float* kr = &kq[n][hh * 16];
        const float* vr = &kq[n][128 + hh * 16];
        float4 k0 = *(const float4*)(kr);
        float4 k1 = *(const float4*)(kr + 4);
        float4 k2 = *(const float4*)(kr + 8);
        float4 k3 = *(const float4*)(kr + 12);
        float4 v0 = *(const float4*)(vr);
        float4 v1 = *(const float4*)(vr + 4);
        float4 v2 = *(const float4*)(vr + 8);
        float4 v3 = *(const float4*)(vr + 12);
        if (vA & ok) {
            float kt = dot16(k0, k1, k2, k3, wkA);
            float vt = dot16(v0, v1, v2, v3, wvA);
            kvt[(size_t)(sbA + n) * 64 + lane] = __float22half2_rn(make_float2(kt, vt));
        }
        if (vB & ok) {
            float kt = dot16(k0, k1, k2, k3, wkB);
            float vt = dot16(v0, v1, v2, v3, wvB);
            kvt[(size_t)(sbB + n) * 64 + lane] = __float22half2_rn(make_float2(kt, vt));
        }
    }
}

// -------- fused gather: score + online softmax + message agg (R6 codegen) --------
__global__ __launch_bounds__(512)
void k_gather(float* __restrict__ qagg, const __half2* __restrict__ kvt,
              const int* __restrict__ row_ptr, const int* __restrict__ csr) {
    int wave = threadIdx.x >> 6, lane = threadIdx.x & 63;
    int node = blockIdx.x * 8 + wave;
    if (node >= NTOT) return;
    float q = qagg[(size_t)node * 64 + lane];   // q[h][x]
    int beg = row_ptr[node], end = row_ptr[node + 1];
    float m = -1e30f, l = 0.f, acc = 0.f;
    for (int base = beg; base < end; base += 64) {
        int n = end - base; if (n > 64) n = 64;
        int ent = csr[base + ((lane < n) ? lane : 0)];   // 64 entries in one load
        for (int c = 0; c < n; c += 8) {
            int cn = n - c; if (cn > 8) cn = 8;
            __half2 f[8];
            #pragma unroll
            for (int k = 0; k < 8; k++) {               // batch 8 gathers (MLP)
                int idx = c + ((k < cn) ? k : 0);
                int sl = __shfl(ent, idx, 64);
                f[k] = kvt[(size_t)sl * 64 + lane];
            }
            #pragma unroll
            for (int k = 0; k < 8; k++) {
                if (k >= cn) break;
                float2 kv2 = __half22float2(f[k]);
                float s = q * kv2.x;
                s += __shfl_xor(s, 1, 64); s += __shfl_xor(s, 2, 64);
                s += __shfl_xor(s, 4, 64); s += __shfl_xor(s, 8, 64);
                float d2 = s - m;
                float t = __expf(-fabsf(d2));   // one exp per edge
                bool pos = d2 > 0.f;
                m = fmaxf(m, s);
                float sc1 = pos ? t : 1.f;
                float es  = pos ? 1.f : t;
                l   = l * sc1 + es;
                acc = acc * sc1 + es * kv2.y;
            }
        }
    }
    qagg[(size_t)node * 64 + lane] = (l > 0.f) ? acc / l : 0.f;
}

// ------- epilogue: gelu -> @Wout + bout -> skip-gate -> relu [-> l2norm on last]
__global__ __launch_bounds__(256)
void k_out(const float* __restrict__ agg, const float* __restrict__ Wout,
           const float* __restrict__ bout, const float* __restrict__ skip,
           float* __restrict__ h, float* __restrict__ out, int layer, int last) {
    int b = blockIdx.x; int t, n0, lim;
    if (b < 938)       { t = 0; n0 = b * 32;                 lim = NU; }
    else if (b < 2813) { t = 1; n0 = NU + (b - 938) * 32;    lim = NU + NE_; }
    else               { t = 2; n0 = NU + NE_ + (b - 2813) * 32; lim = NTOT; }
    int nn = min(32, lim - n0);
    __shared__ float gs[32][64];
    for (int i = threadIdx.x; i < nn * 64; i += 256) {
        float o = agg[(size_t)n0 * 64 + i];
        gs[i >> 6][i & 63] = 0.5f * o * (1.f + erff(o * 0.70710678118654752f));
    }
    __syncthreads();
    int j = threadIdx.x & 63, g = threadIdx.x >> 6;   // 4 waves x 8 nodes
    const float* W = Wout + (size_t)(layer * 3 + t) * HID * HID;
    float bb = bout[(layer * 3 + t) * HID + j];
    float acc[8];
    #pragma unroll
    for (int n = 0; n < 8; n++) acc[n] = bb;
    for (int i = 0; i < 64; i++) {
        float w = W[i * 64 + j];
        #pragma unroll
        for (int n = 0; n < 8; n++) acc[n] += gs[g * 8 + n][i] * w;
    }
    float gk = 1.f / (1.f + __expf(-skip[layer * 3 + t]));
    #pragma unroll
    for (int n = 0; n < 8; n++) {
        int node = n0 + g * 8 + n;
        if (node >= lim) continue;
        float r = gk * acc[n] + (1.f - gk) * h[(size_t)node * 64 + j];
        r = fmaxf(r, 0.f);                              // relu
        if (!last) {
            h[(size_t)node * 64 + j] = r;
        } else {                                        // fused l2 normalize
            float ss = r * r;
            ss += __shfl_xor(ss, 1, 64);  ss += __shfl_xor(ss, 2, 64);
            ss += __shfl_xor(ss, 4, 64);  ss += __shfl_xor(ss, 8, 64);
            ss += __shfl_xor(ss, 16, 64); ss += __shfl_xor(ss, 32, 64);
            float nrm = fmaxf(sqrtf(ss), 1e-12f);
            out[(size_t)node * 64 + j] = r / nrm;
        }
    }
}

extern "C" void kernel_launch(void* const* d_in, const int* in_sizes, int n_in,
                              void* d_out, int out_size, void* d_ws, size_t ws_size,
                              hipStream_t stream) {
    const float* xu   = (const float*)d_in[0];
    const float* xe   = (const float*)d_in[1];
    const float* xv   = (const float*)d_in[2];
    const float* Wu   = (const float*)d_in[3];
    const float* bu   = (const float*)d_in[4];
    const float* We   = (const float*)d_in[5];
    const float* be   = (const float*)d_in[6];
    const float* Wv_  = (const float*)d_in[7];
    const float* bv   = (const float*)d_in[8];
    const float* embu = (const float*)d_in[9];
    const float* embe = (const float*)d_in[10];
    const float* embv = (const float*)d_in[11];
    const float* Wkqv = (const float*)d_in[12];
    const float* bkqv = (const float*)d_in[13];
    const float* Wk   = (const float*)d_in[14];
    const float* Wv   = (const float*)d_in[15];
    const float* prel = (const float*)d_in[16];
    const float* Wout = (const float*)d_in[17];
    const float* bout = (const float*)d_in[18];
    const float* skip = (const float*)d_in[19];
    const int*   idu  = (const int*)d_in[20];
    const int*   ide  = (const int*)d_in[21];
    const int*   idv  = (const int*)d_in[22];
    EdgePtrs ep;
    for (int e = 0; e < 13; e++) ep.p[e] = (const int*)d_in[23 + e];

    float* ws  = (float*)d_ws;
    float* h      = ws;                                    // NTOT*64 f32
    float* qagg   = h    + (size_t)NTOT * HID;             // NTOT*64 f32 (q, then agg)
    __half2* kvt  = (__half2*)(qagg + (size_t)NTOT * HID); // NSLOT*64 half2
    int* cnt     = (int*)(kvt + (size_t)NSLOT * HID);      // NTOT
    int* cursor  = cnt + NTOT;                             // NTOT
    int* row_ptr = cursor + NTOT;                          // NTOT+1
    int* partial = row_ptr + NTOT + 1;                     // 512
    int* csr     = partial + 512;                          // ETOT int

    k_init<<<(NTOT * HID + 255) / 256, 256, 0, stream>>>(
        xu, xe, xv, Wu, bu, We, be, Wv_, bv, embu, embe, embv, idu, ide, idv, h);

    // CSR build (edges are layer-invariant); exact rows, entry = slot id
    hipMemsetAsync(cnt, 0, (size_t)2 * NTOT * 4, stream);   // cnt + cursor
    int nblk = (NTOT + 255) / 256;   // 356
    k_cnt<<<(ETOT + 255) / 256, 256, 0, stream>>>(ep, cnt);
    k_scan_a<<<nblk, 256, 0, stream>>>(cnt, partial);
    k_scan_b<<<1, 512, 0, stream>>>(partial, nblk);
    k_scan_c<<<nblk, 256, 0, stream>>>(cnt, partial, row_ptr);
    k_fill<<<(ETOT + 255) / 256, 256, 0, stream>>>(ep, row_ptr, cursor, csr);

    for (int l = 0; l < LAYERS; l++) {
        k_kqvt<<<(NTOT + 15) / 16, 192, 0, stream>>>(h, Wkqv, bkqv, Wk, Wv, prel,
                                                     qagg, kvt, l);
        k_gather<<<(NTOT + 7) / 8, 512, 0, stream>>>(qagg, kvt, row_ptr, csr);
        k_out<<<2845, 256, 0, stream>>>(qagg, Wout, bout, skip, h,
                                        (float*)d_out, l, l == LAYERS - 1);
    }
}